// Round 1
// baseline (1948.971 us; speedup 1.0000x reference)
//
#include <hip/hip_runtime.h>
#include <math.h>

// Problem constants
#define L_SEQ 2048
#define DM    768
#define DI    1536          // d_inner
#define DTR   48            // dt_rank
#define DST   16            // d_state
#define XDW   80            // dt_rank + 2*d_state
#define NCH   64            // scan chunks
#define LC    32            // L_SEQ / NCH

__device__ __forceinline__ float silu_f(float x) {
    return x / (1.0f + __expf(-x));
}

// ---------------------------------------------------------------------------
// Embedding gather: x[l, :] = emb[ids[l], :]   (float4 over 768 = 192 f4)
// ---------------------------------------------------------------------------
__global__ __launch_bounds__(256) void embed_kernel(
    const int* __restrict__ ids, const float* __restrict__ emb,
    float* __restrict__ x)
{
    int idx = blockIdx.x * 256 + threadIdx.x;          // over L_SEQ * 192
    if (idx >= L_SEQ * (DM / 4)) return;
    int row = idx / (DM / 4);
    int col = idx % (DM / 4);
    ((float4*)x)[idx] = ((const float4*)emb)[(size_t)ids[row] * (DM / 4) + col];
}

// ---------------------------------------------------------------------------
// RMSNorm: one block per row of x (2048 rows, D=768)
// ---------------------------------------------------------------------------
__global__ __launch_bounds__(256) void rmsnorm_kernel(
    const float* __restrict__ x, const float* __restrict__ w,
    float* __restrict__ out)
{
    int row = blockIdx.x;
    const float* xr = x + (size_t)row * DM;
    float s = 0.f;
    for (int i = threadIdx.x; i < DM; i += 256) { float v = xr[i]; s += v * v; }
    #pragma unroll
    for (int off = 32; off > 0; off >>= 1) s += __shfl_down(s, off, 64);
    __shared__ float ws[4];
    int wave = threadIdx.x >> 6, lane = threadIdx.x & 63;
    if (lane == 0) ws[wave] = s;
    __syncthreads();
    float tot = ws[0] + ws[1] + ws[2] + ws[3];
    float rs = rsqrtf(tot / (float)DM + 1e-5f);
    for (int i = threadIdx.x; i < DM; i += 256)
        out[(size_t)row * DM + i] = xr[i] * rs * w[i];
}

// ---------------------------------------------------------------------------
// Generic fp32 GEMM: C[M,N] = A[M,K] @ B[K,N]
//   MODE 0: store     MODE 1: softplus(acc + bias[col])     MODE 2: C += acc
// 64x64 block tile, BK=16, 256 threads, 4x4 per thread
// ---------------------------------------------------------------------------
template <int MODE>
__global__ __launch_bounds__(256) void gemm_f32(
    const float* __restrict__ A, int lda,
    const float* __restrict__ B, int ldb,
    float* __restrict__ C, int ldc,
    int M, int N, int K,
    const float* __restrict__ bias)
{
    const int BM = 64, BN = 64, BK = 16;
    __shared__ __align__(16) float As[BK][BM + 4];
    __shared__ __align__(16) float Bs[BK][BN + 4];
    int tid = threadIdx.x;
    int brow = blockIdx.y * BM;
    int bcol = blockIdx.x * BN;
    int ty = tid >> 4, tx = tid & 15;

    float acc[4][4] = {};

    for (int k0 = 0; k0 < K; k0 += BK) {
        #pragma unroll
        for (int i = 0; i < 4; i++) {
            int idx = tid + i * 256;           // 0..1023 over 64x16 A tile
            int m = idx >> 4, k = idx & 15;
            int gm = brow + m, gk = k0 + k;
            As[k][m] = (gm < M && gk < K) ? A[(size_t)gm * lda + gk] : 0.f;
        }
        #pragma unroll
        for (int i = 0; i < 4; i++) {
            int idx = tid + i * 256;           // 0..1023 over 16x64 B tile
            int k = idx >> 6, n = idx & 63;
            int gk = k0 + k, gn = bcol + n;
            Bs[k][n] = (gk < K && gn < N) ? B[(size_t)gk * ldb + gn] : 0.f;
        }
        __syncthreads();
        #pragma unroll
        for (int k = 0; k < BK; k++) {
            float4 av = *(const float4*)&As[k][ty * 4];
            float4 bv = *(const float4*)&Bs[k][tx * 4];
            float a[4] = {av.x, av.y, av.z, av.w};
            float b[4] = {bv.x, bv.y, bv.z, bv.w};
            #pragma unroll
            for (int i = 0; i < 4; i++)
                #pragma unroll
                for (int j = 0; j < 4; j++)
                    acc[i][j] += a[i] * b[j];
        }
        __syncthreads();
    }

    #pragma unroll
    for (int i = 0; i < 4; i++) {
        int row = brow + ty * 4 + i;
        if (row >= M) continue;
        #pragma unroll
        for (int j = 0; j < 4; j++) {
            int col = bcol + tx * 4 + j;
            if (col >= N) continue;
            float v = acc[i][j];
            if (MODE == 0) {
                C[(size_t)row * ldc + col] = v;
            } else if (MODE == 1) {
                v += bias[col];
                C[(size_t)row * ldc + col] = (v > 20.f) ? v : log1pf(__expf(v));
            } else {
                C[(size_t)row * ldc + col] += v;
            }
        }
    }
}

// ---------------------------------------------------------------------------
// Causal depthwise conv (width 4) + bias + SiLU.
// xz column slice [:,0:1536] (row stride 2*DI) -> xr (L x DI)
// ---------------------------------------------------------------------------
__global__ __launch_bounds__(256) void conv_silu_kernel(
    const float* __restrict__ xz, const float* __restrict__ w,
    const float* __restrict__ b, float* __restrict__ xr)
{
    int idx = blockIdx.x * 256 + threadIdx.x;          // over L_SEQ*DI
    if (idx >= L_SEQ * DI) return;
    int l = idx / DI, c = idx % DI;
    float4 wc = ((const float4*)w)[c];
    const float* col = xz + c;
    float acc = b[c];
    if (l >= 3) {
        acc += wc.x * col[(size_t)(l - 3) * (2 * DI)]
             + wc.y * col[(size_t)(l - 2) * (2 * DI)]
             + wc.z * col[(size_t)(l - 1) * (2 * DI)]
             + wc.w * col[(size_t)l * (2 * DI)];
    } else {
        const float wv[4] = {wc.x, wc.y, wc.z, wc.w};
        for (int k = 0; k < 4; k++) {
            int ls = l - 3 + k;
            if (ls >= 0) acc += wv[k] * col[(size_t)ls * (2 * DI)];
        }
    }
    xr[idx] = silu_f(acc);
}

// ---------------------------------------------------------------------------
// Selective scan — pass A: per chunk c, per channel d, compute
//   P[n]   = prod_{l in chunk} exp(delta*A[n])
//   hfin[n]= local scan final state (zero initial)
// Layout of aprod/hfin/hin: [c][d][n] = (c*DI + d)*DST + n
// ---------------------------------------------------------------------------
__global__ __launch_bounds__(256) void scan_passA(
    const float* __restrict__ delta, const float* __restrict__ xr,
    const float* __restrict__ xdbl, const float* __restrict__ A_log,
    float* __restrict__ aprod, float* __restrict__ hfin)
{
    int d = blockIdx.x * 256 + threadIdx.x;            // 0..DI-1
    int c = blockIdx.y;
    if (d >= DI) return;

    float Alog[DST], Aloc[DST], h[DST], P[DST];
    *(float4*)&Alog[0]  = *(const float4*)&A_log[(size_t)d * DST + 0];
    *(float4*)&Alog[4]  = *(const float4*)&A_log[(size_t)d * DST + 4];
    *(float4*)&Alog[8]  = *(const float4*)&A_log[(size_t)d * DST + 8];
    *(float4*)&Alog[12] = *(const float4*)&A_log[(size_t)d * DST + 12];
    #pragma unroll
    for (int n = 0; n < DST; n++) { Aloc[n] = -__expf(Alog[n]); h[n] = 0.f; P[n] = 1.f; }

    int l0 = c * LC;
    for (int l = l0; l < l0 + LC; l++) {
        float dl = delta[(size_t)l * DI + d];
        float ul = xr[(size_t)l * DI + d];
        float du = dl * ul;
        float Bv[DST];
        const float4* B4 = (const float4*)(xdbl + (size_t)l * XDW + DTR);
        *(float4*)&Bv[0] = B4[0]; *(float4*)&Bv[4] = B4[1];
        *(float4*)&Bv[8] = B4[2]; *(float4*)&Bv[12] = B4[3];
        #pragma unroll
        for (int n = 0; n < DST; n++) {
            float da = __expf(dl * Aloc[n]);
            h[n] = h[n] * da + du * Bv[n];
            P[n] *= da;
        }
    }
    size_t base = ((size_t)c * DI + d) * DST;
    #pragma unroll
    for (int n = 0; n < DST; n += 4) {
        *(float4*)&aprod[base + n] = *(float4*)&P[n];
        *(float4*)&hfin[base + n]  = *(float4*)&h[n];
    }
}

// ---------------------------------------------------------------------------
// Pass B: sequential carry over chunks. hin[c] = state entering chunk c.
// ---------------------------------------------------------------------------
__global__ __launch_bounds__(256) void scan_passB(
    const float* __restrict__ aprod, const float* __restrict__ hfin,
    float* __restrict__ hin)
{
    int idx = blockIdx.x * 256 + threadIdx.x;          // over DI*DST = 24576
    if (idx >= DI * DST) return;
    float cur = 0.f;
    for (int c = 0; c < NCH; c++) {
        size_t o = (size_t)c * DI * DST + idx;
        hin[o] = cur;
        cur = hfin[o] + aprod[o] * cur;
    }
}

// ---------------------------------------------------------------------------
// Pass C: replay chunk with correct carry; fuse y = sum_n h*C + u*D and
// y2 = y * silu(res)  (res = xz[:, DI:2*DI])
// ---------------------------------------------------------------------------
__global__ __launch_bounds__(256) void scan_passC(
    const float* __restrict__ delta, const float* __restrict__ xr,
    const float* __restrict__ xdbl, const float* __restrict__ A_log,
    const float* __restrict__ Dp, const float* __restrict__ hin,
    const float* __restrict__ xz, float* __restrict__ y2)
{
    int d = blockIdx.x * 256 + threadIdx.x;
    int c = blockIdx.y;
    if (d >= DI) return;

    float Alog[DST], Aloc[DST], h[DST];
    *(float4*)&Alog[0]  = *(const float4*)&A_log[(size_t)d * DST + 0];
    *(float4*)&Alog[4]  = *(const float4*)&A_log[(size_t)d * DST + 4];
    *(float4*)&Alog[8]  = *(const float4*)&A_log[(size_t)d * DST + 8];
    *(float4*)&Alog[12] = *(const float4*)&A_log[(size_t)d * DST + 12];
    size_t base = ((size_t)c * DI + d) * DST;
    #pragma unroll
    for (int n = 0; n < DST; n += 4) *(float4*)&h[n] = *(const float4*)&hin[base + n];
    #pragma unroll
    for (int n = 0; n < DST; n++) Aloc[n] = -__expf(Alog[n]);
    float Dd = Dp[d];

    int l0 = c * LC;
    for (int l = l0; l < l0 + LC; l++) {
        float dl = delta[(size_t)l * DI + d];
        float ul = xr[(size_t)l * DI + d];
        float du = dl * ul;
        float Bv[DST], Cv[DST];
        const float4* B4 = (const float4*)(xdbl + (size_t)l * XDW + DTR);
        const float4* C4 = (const float4*)(xdbl + (size_t)l * XDW + DTR + DST);
        *(float4*)&Bv[0] = B4[0]; *(float4*)&Bv[4] = B4[1];
        *(float4*)&Bv[8] = B4[2]; *(float4*)&Bv[12] = B4[3];
        *(float4*)&Cv[0] = C4[0]; *(float4*)&Cv[4] = C4[1];
        *(float4*)&Cv[8] = C4[2]; *(float4*)&Cv[12] = C4[3];
        float y = 0.f;
        #pragma unroll
        for (int n = 0; n < DST; n++) {
            float da = __expf(dl * Aloc[n]);
            h[n] = h[n] * da + du * Bv[n];
            y += h[n] * Cv[n];
        }
        y += ul * Dd;
        float r = xz[(size_t)l * (2 * DI) + DI + d];
        y2[(size_t)l * DI + d] = y * silu_f(r);
    }
}

// ---------------------------------------------------------------------------
// Host launch
// ---------------------------------------------------------------------------
extern "C" void kernel_launch(void* const* d_in, const int* in_sizes, int n_in,
                              void* d_out, int out_size, void* d_ws, size_t ws_size,
                              hipStream_t stream)
{
    const int*   ids       = (const int*)d_in[0];
    const float* emb       = (const float*)d_in[1];
    const float* norm_w    = (const float*)d_in[2];
    const float* in_proj_w = (const float*)d_in[3];
    const float* conv_w    = (const float*)d_in[4];
    const float* conv_b    = (const float*)d_in[5];
    const float* x_proj_w  = (const float*)d_in[6];
    const float* dt_proj_w = (const float*)d_in[7];
    const float* dt_proj_b = (const float*)d_in[8];
    const float* A_log     = (const float*)d_in[9];
    const float* Dp        = (const float*)d_in[10];
    const float* out_proj_w= (const float*)d_in[11];

    float* x = (float*)d_out;                 // running residual (L x DM)

    // Workspace carve-up (floats)
    float* ws = (float*)d_ws;
    float* xn    = ws;  ws += (size_t)L_SEQ * DM;        // 1.57M
    float* xz    = ws;  ws += (size_t)L_SEQ * 2 * DI;    // 6.29M
    float* xr    = ws;  ws += (size_t)L_SEQ * DI;        // 3.15M
    float* xdbl  = ws;  ws += (size_t)L_SEQ * XDW;       // 164K
    float* delta = ws;  ws += (size_t)L_SEQ * DI;        // 3.15M
    float* y2    = ws;  ws += (size_t)L_SEQ * DI;        // 3.15M
    float* aprod = ws;  ws += (size_t)NCH * DI * DST;    // 1.57M
    float* hfin  = ws;  ws += (size_t)NCH * DI * DST;    // 1.57M
    float* hin   = ws;  ws += (size_t)NCH * DI * DST;    // 1.57M

    // Embedding
    embed_kernel<<<(L_SEQ * (DM / 4) + 255) / 256, 256, 0, stream>>>(ids, emb, x);

    for (int layer = 0; layer < 2; layer++) {
        const float* nw  = norm_w     + (size_t)layer * DM;
        const float* ipw = in_proj_w  + (size_t)layer * DM * 2 * DI;
        const float* cw  = conv_w     + (size_t)layer * DI * 4;
        const float* cb  = conv_b     + (size_t)layer * DI;
        const float* xpw = x_proj_w   + (size_t)layer * DI * XDW;
        const float* dpw = dt_proj_w  + (size_t)layer * DTR * DI;
        const float* dpb = dt_proj_b  + (size_t)layer * DI;
        const float* al  = A_log      + (size_t)layer * DI * DST;
        const float* dpp = Dp         + (size_t)layer * DI;
        const float* opw = out_proj_w + (size_t)layer * DI * DM;

        // 1. RMSNorm
        rmsnorm_kernel<<<L_SEQ, 256, 0, stream>>>(x, nw, xn);

        // 2. xz = xn @ in_proj_w   (2048 x 3072, K=768)
        gemm_f32<0><<<dim3(2 * DI / 64, L_SEQ / 64), 256, 0, stream>>>(
            xn, DM, ipw, 2 * DI, xz, 2 * DI, L_SEQ, 2 * DI, DM, nullptr);

        // 3. causal depthwise conv + silu -> xr
        conv_silu_kernel<<<(L_SEQ * DI) / 256, 256, 0, stream>>>(xz, cw, cb, xr);

        // 4. x_dbl = xr @ x_proj_w  (2048 x 80, K=1536)
        gemm_f32<0><<<dim3((XDW + 63) / 64, L_SEQ / 64), 256, 0, stream>>>(
            xr, DI, xpw, XDW, xdbl, XDW, L_SEQ, XDW, DI, nullptr);

        // 5. delta = softplus(dt @ dt_proj_w + b)  (2048 x 1536, K=48)
        gemm_f32<1><<<dim3(DI / 64, L_SEQ / 64), 256, 0, stream>>>(
            xdbl, XDW, dpw, DI, delta, DI, L_SEQ, DI, DTR, dpb);

        // 6. selective scan (3-pass chunked) fused with gating -> y2
        scan_passA<<<dim3(DI / 256, NCH), 256, 0, stream>>>(
            delta, xr, xdbl, al, aprod, hfin);
        scan_passB<<<(DI * DST) / 256, 256, 0, stream>>>(aprod, hfin, hin);
        scan_passC<<<dim3(DI / 256, NCH), 256, 0, stream>>>(
            delta, xr, xdbl, al, dpp, hin, xz, y2);

        // 7. x += y2 @ out_proj_w  (2048 x 768, K=1536)
        gemm_f32<2><<<dim3(DM / 64, L_SEQ / 64), 256, 0, stream>>>(
            y2, DI, opw, DM, x, DM, L_SEQ, DM, DI, nullptr);
    }
}

// Round 2
// 1026.894 us; speedup vs baseline: 1.8979x; 1.8979x over previous
//
#include <hip/hip_runtime.h>
#include <math.h>

// Problem constants
#define L_SEQ 2048
#define DM    768
#define DI    1536          // d_inner
#define DTR   48            // dt_rank
#define DST   16            // d_state
#define XDW   80            // dt_rank + 2*d_state
#define NCH   64            // scan chunks
#define LC    32            // L_SEQ / NCH

typedef short bf16x8 __attribute__((ext_vector_type(8)));
typedef float f32x4  __attribute__((ext_vector_type(4)));

__device__ __forceinline__ float silu_f(float x) {
    return x / (1.0f + __expf(-x));
}

// round-to-nearest-even float -> bf16 bits
__device__ __forceinline__ short f2bf(float x) {
    union { float f; unsigned u; } v; v.f = x;
    unsigned r = v.u + 0x7fff + ((v.u >> 16) & 1);
    return (short)(r >> 16);
}

// ---------------------------------------------------------------------------
// Embedding gather
// ---------------------------------------------------------------------------
__global__ __launch_bounds__(256) void embed_kernel(
    const int* __restrict__ ids, const float* __restrict__ emb,
    float* __restrict__ x)
{
    int idx = blockIdx.x * 256 + threadIdx.x;
    if (idx >= L_SEQ * (DM / 4)) return;
    int row = idx / (DM / 4);
    int col = idx % (DM / 4);
    ((float4*)x)[idx] = ((const float4*)emb)[(size_t)ids[row] * (DM / 4) + col];
}

// ---------------------------------------------------------------------------
// RMSNorm: one block per row; writes bf16 output (feeds bf16 MFMA GEMM)
// ---------------------------------------------------------------------------
__global__ __launch_bounds__(256) void rmsnorm_kernel(
    const float* __restrict__ x, const float* __restrict__ w,
    short* __restrict__ out)
{
    int row = blockIdx.x;
    const float* xr = x + (size_t)row * DM;
    float s = 0.f;
    for (int i = threadIdx.x; i < DM; i += 256) { float v = xr[i]; s += v * v; }
    #pragma unroll
    for (int off = 32; off > 0; off >>= 1) s += __shfl_down(s, off, 64);
    __shared__ float ws[4];
    int wave = threadIdx.x >> 6, lane = threadIdx.x & 63;
    if (lane == 0) ws[wave] = s;
    __syncthreads();
    float tot = ws[0] + ws[1] + ws[2] + ws[3];
    float rs = rsqrtf(tot / (float)DM + 1e-5f);
    for (int i = threadIdx.x; i < DM; i += 256)
        out[(size_t)row * DM + i] = f2bf(xr[i] * rs * w[i]);
}

// ---------------------------------------------------------------------------
// Transpose + fp32->bf16: W[K][N] -> Bt[N][K].  K,N multiples of 32.
// ---------------------------------------------------------------------------
__global__ __launch_bounds__(256) void transpose_bf16_kernel(
    const float* __restrict__ W, short* __restrict__ Bt, int K, int N)
{
    __shared__ float tile[32][33];
    int n0 = blockIdx.x * 32, k0 = blockIdx.y * 32;
    int tx = threadIdx.x & 31, ty = threadIdx.x >> 5;   // ty 0..7
    #pragma unroll
    for (int i = 0; i < 4; i++)
        tile[ty + i * 8][tx] = W[(size_t)(k0 + ty + i * 8) * N + n0 + tx];
    __syncthreads();
    #pragma unroll
    for (int i = 0; i < 4; i++)
        Bt[(size_t)(n0 + ty + i * 8) * K + k0 + tx] = f2bf(tile[tx][ty + i * 8]);
}

// ---------------------------------------------------------------------------
// bf16 MFMA GEMM (m97 structure): C[M,N] = A[M,K] @ Bt[N,K]^T
// 128x128 tile, BK=32, 256 thr = 4 waves (2x2), 4x4 16x16x32 MFMA per wave.
// M,N multiples of 128; K multiple of 32.
//   MODE 0: C = acc      MODE 2: C += acc
// ---------------------------------------------------------------------------
template <int MODE>
__global__ __launch_bounds__(256) void gemm_bf16_bt(
    const short* __restrict__ A, const short* __restrict__ Bt,
    float* __restrict__ C, int M, int N, int K)
{
    __shared__ short As[128 * 32];
    __shared__ short Bs[128 * 32];
    int tid  = threadIdx.x;
    int lane = tid & 63;
    int w    = tid >> 6;
    int wr = w >> 1, wc = w & 1;
    int brow = blockIdx.y * 128, bcol = blockIdx.x * 128;

    f32x4 acc[4][4] = {};

    for (int k0 = 0; k0 < K; k0 += 32) {
        // stage 128x32 bf16 tiles of A and Bt via global_load_lds (16B/lane)
        #pragma unroll
        for (int i = 0; i < 2; i++) {
            int c = tid + i * 256;        // 0..511 chunks of 16B
            int r = c >> 2, q = c & 3;    // row, 16B-chunk within row
            const short* ga = A  + (size_t)(brow + r) * K + k0 + q * 8;
            const short* gb = Bt + (size_t)(bcol + r) * K + k0 + q * 8;
            __builtin_amdgcn_global_load_lds(
                (const __attribute__((address_space(1))) void*)ga,
                (__attribute__((address_space(3))) void*)&As[r * 32 + q * 8],
                16, 0, 0);
            __builtin_amdgcn_global_load_lds(
                (const __attribute__((address_space(1))) void*)gb,
                (__attribute__((address_space(3))) void*)&Bs[r * 32 + q * 8],
                16, 0, 0);
        }
        __syncthreads();

        bf16x8 af[4], bf[4];
        int kh = (lane >> 4) * 8;
        int ml = lane & 15;
        #pragma unroll
        for (int t = 0; t < 4; t++) {
            af[t] = *(const bf16x8*)&As[(wr * 64 + t * 16 + ml) * 32 + kh];
            bf[t] = *(const bf16x8*)&Bs[(wc * 64 + t * 16 + ml) * 32 + kh];
        }
        #pragma unroll
        for (int mt = 0; mt < 4; mt++)
            #pragma unroll
            for (int nt = 0; nt < 4; nt++)
                acc[mt][nt] = __builtin_amdgcn_mfma_f32_16x16x32_bf16(
                    af[mt], bf[nt], acc[mt][nt], 0, 0, 0);
        __syncthreads();
    }

    // epilogue: C/D layout col=lane&15, row=(lane>>4)*4+reg
    int r0 = (lane >> 4) * 4, c0 = lane & 15;
    #pragma unroll
    for (int mt = 0; mt < 4; mt++) {
        #pragma unroll
        for (int nt = 0; nt < 4; nt++) {
            #pragma unroll
            for (int reg = 0; reg < 4; reg++) {
                int row = brow + wr * 64 + mt * 16 + r0 + reg;
                int col = bcol + wc * 64 + nt * 16 + c0;
                float v = acc[mt][nt][reg];
                if (MODE == 0) C[(size_t)row * N + col] = v;
                else           C[(size_t)row * N + col] += v;
            }
        }
    }
}

// ---------------------------------------------------------------------------
// Generic fp32 GEMM (small GEMMs: x_proj, dt_proj)
//   MODE 0: store     MODE 1: softplus(acc + bias[col])
// ---------------------------------------------------------------------------
template <int MODE>
__global__ __launch_bounds__(256) void gemm_f32(
    const float* __restrict__ A, int lda,
    const float* __restrict__ B, int ldb,
    float* __restrict__ C, int ldc,
    int M, int N, int K,
    const float* __restrict__ bias)
{
    const int BM = 64, BN = 64, BK = 16;
    __shared__ __align__(16) float As[BK][BM + 4];
    __shared__ __align__(16) float Bs[BK][BN + 4];
    int tid = threadIdx.x;
    int brow = blockIdx.y * BM;
    int bcol = blockIdx.x * BN;
    int ty = tid >> 4, tx = tid & 15;

    float acc[4][4] = {};

    for (int k0 = 0; k0 < K; k0 += BK) {
        #pragma unroll
        for (int i = 0; i < 4; i++) {
            int idx = tid + i * 256;
            int m = idx >> 4, k = idx & 15;
            int gm = brow + m, gk = k0 + k;
            As[k][m] = (gm < M && gk < K) ? A[(size_t)gm * lda + gk] : 0.f;
        }
        #pragma unroll
        for (int i = 0; i < 4; i++) {
            int idx = tid + i * 256;
            int k = idx >> 6, n = idx & 63;
            int gk = k0 + k, gn = bcol + n;
            Bs[k][n] = (gk < K && gn < N) ? B[(size_t)gk * ldb + gn] : 0.f;
        }
        __syncthreads();
        #pragma unroll
        for (int k = 0; k < BK; k++) {
            float4 av = *(const float4*)&As[k][ty * 4];
            float4 bv = *(const float4*)&Bs[k][tx * 4];
            float a[4] = {av.x, av.y, av.z, av.w};
            float b[4] = {bv.x, bv.y, bv.z, bv.w};
            #pragma unroll
            for (int i = 0; i < 4; i++)
                #pragma unroll
                for (int j = 0; j < 4; j++)
                    acc[i][j] += a[i] * b[j];
        }
        __syncthreads();
    }

    #pragma unroll
    for (int i = 0; i < 4; i++) {
        int row = brow + ty * 4 + i;
        if (row >= M) continue;
        #pragma unroll
        for (int j = 0; j < 4; j++) {
            int col = bcol + tx * 4 + j;
            if (col >= N) continue;
            float v = acc[i][j];
            if (MODE == 0) {
                C[(size_t)row * ldc + col] = v;
            } else {
                v += bias[col];
                C[(size_t)row * ldc + col] = (v > 20.f) ? v : log1pf(__expf(v));
            }
        }
    }
}

// ---------------------------------------------------------------------------
// Causal depthwise conv (width 4) + bias + SiLU
// ---------------------------------------------------------------------------
__global__ __launch_bounds__(256) void conv_silu_kernel(
    const float* __restrict__ xz, const float* __restrict__ w,
    const float* __restrict__ b, float* __restrict__ xr)
{
    int idx = blockIdx.x * 256 + threadIdx.x;
    if (idx >= L_SEQ * DI) return;
    int l = idx / DI, c = idx % DI;
    float4 wc = ((const float4*)w)[c];
    const float* col = xz + c;
    float acc = b[c];
    if (l >= 3) {
        acc += wc.x * col[(size_t)(l - 3) * (2 * DI)]
             + wc.y * col[(size_t)(l - 2) * (2 * DI)]
             + wc.z * col[(size_t)(l - 1) * (2 * DI)]
             + wc.w * col[(size_t)l * (2 * DI)];
    } else {
        const float wv[4] = {wc.x, wc.y, wc.z, wc.w};
        for (int k = 0; k < 4; k++) {
            int ls = l - 3 + k;
            if (ls >= 0) acc += wv[k] * col[(size_t)ls * (2 * DI)];
        }
    }
    xr[idx] = silu_f(acc);
}

// ---------------------------------------------------------------------------
// Selective scan pass A
// ---------------------------------------------------------------------------
__global__ __launch_bounds__(256) void scan_passA(
    const float* __restrict__ delta, const float* __restrict__ xr,
    const float* __restrict__ xdbl, const float* __restrict__ A_log,
    float* __restrict__ aprod, float* __restrict__ hfin)
{
    int d = blockIdx.x * 256 + threadIdx.x;
    int c = blockIdx.y;
    if (d >= DI) return;

    float Alog[DST], Aloc[DST], h[DST], P[DST];
    *(float4*)&Alog[0]  = *(const float4*)&A_log[(size_t)d * DST + 0];
    *(float4*)&Alog[4]  = *(const float4*)&A_log[(size_t)d * DST + 4];
    *(float4*)&Alog[8]  = *(const float4*)&A_log[(size_t)d * DST + 8];
    *(float4*)&Alog[12] = *(const float4*)&A_log[(size_t)d * DST + 12];
    #pragma unroll
    for (int n = 0; n < DST; n++) { Aloc[n] = -__expf(Alog[n]); h[n] = 0.f; P[n] = 1.f; }

    int l0 = c * LC;
    for (int l = l0; l < l0 + LC; l++) {
        float dl = delta[(size_t)l * DI + d];
        float ul = xr[(size_t)l * DI + d];
        float du = dl * ul;
        float Bv[DST];
        const float4* B4 = (const float4*)(xdbl + (size_t)l * XDW + DTR);
        *(float4*)&Bv[0] = B4[0]; *(float4*)&Bv[4] = B4[1];
        *(float4*)&Bv[8] = B4[2]; *(float4*)&Bv[12] = B4[3];
        #pragma unroll
        for (int n = 0; n < DST; n++) {
            float da = __expf(dl * Aloc[n]);
            h[n] = h[n] * da + du * Bv[n];
            P[n] *= da;
        }
    }
    size_t base = ((size_t)c * DI + d) * DST;
    #pragma unroll
    for (int n = 0; n < DST; n += 4) {
        *(float4*)&aprod[base + n] = *(float4*)&P[n];
        *(float4*)&hfin[base + n]  = *(float4*)&h[n];
    }
}

// ---------------------------------------------------------------------------
// Pass B: sequential carry over chunks
// ---------------------------------------------------------------------------
__global__ __launch_bounds__(256) void scan_passB(
    const float* __restrict__ aprod, const float* __restrict__ hfin,
    float* __restrict__ hin)
{
    int idx = blockIdx.x * 256 + threadIdx.x;
    if (idx >= DI * DST) return;
    float cur = 0.f;
    for (int c = 0; c < NCH; c++) {
        size_t o = (size_t)c * DI * DST + idx;
        hin[o] = cur;
        cur = hfin[o] + aprod[o] * cur;
    }
}

// ---------------------------------------------------------------------------
// Pass C: replay chunk with carry; fuse y and gating; write bf16 y2
// ---------------------------------------------------------------------------
__global__ __launch_bounds__(256) void scan_passC(
    const float* __restrict__ delta, const float* __restrict__ xr,
    const float* __restrict__ xdbl, const float* __restrict__ A_log,
    const float* __restrict__ Dp, const float* __restrict__ hin,
    const float* __restrict__ xz, short* __restrict__ y2)
{
    int d = blockIdx.x * 256 + threadIdx.x;
    int c = blockIdx.y;
    if (d >= DI) return;

    float Alog[DST], Aloc[DST], h[DST];
    *(float4*)&Alog[0]  = *(const float4*)&A_log[(size_t)d * DST + 0];
    *(float4*)&Alog[4]  = *(const float4*)&A_log[(size_t)d * DST + 4];
    *(float4*)&Alog[8]  = *(const float4*)&A_log[(size_t)d * DST + 8];
    *(float4*)&Alog[12] = *(const float4*)&A_log[(size_t)d * DST + 12];
    size_t base = ((size_t)c * DI + d) * DST;
    #pragma unroll
    for (int n = 0; n < DST; n += 4) *(float4*)&h[n] = *(const float4*)&hin[base + n];
    #pragma unroll
    for (int n = 0; n < DST; n++) Aloc[n] = -__expf(Alog[n]);
    float Dd = Dp[d];

    int l0 = c * LC;
    for (int l = l0; l < l0 + LC; l++) {
        float dl = delta[(size_t)l * DI + d];
        float ul = xr[(size_t)l * DI + d];
        float du = dl * ul;
        float Bv[DST], Cv[DST];
        const float4* B4 = (const float4*)(xdbl + (size_t)l * XDW + DTR);
        const float4* C4 = (const float4*)(xdbl + (size_t)l * XDW + DTR + DST);
        *(float4*)&Bv[0] = B4[0]; *(float4*)&Bv[4] = B4[1];
        *(float4*)&Bv[8] = B4[2]; *(float4*)&Bv[12] = B4[3];
        *(float4*)&Cv[0] = C4[0]; *(float4*)&Cv[4] = C4[1];
        *(float4*)&Cv[8] = C4[2]; *(float4*)&Cv[12] = C4[3];
        float y = 0.f;
        #pragma unroll
        for (int n = 0; n < DST; n++) {
            float da = __expf(dl * Aloc[n]);
            h[n] = h[n] * da + du * Bv[n];
            y += h[n] * Cv[n];
        }
        y += ul * Dd;
        float r = xz[(size_t)l * (2 * DI) + DI + d];
        y2[(size_t)l * DI + d] = f2bf(y * silu_f(r));
    }
}

// ---------------------------------------------------------------------------
// Host launch
// ---------------------------------------------------------------------------
extern "C" void kernel_launch(void* const* d_in, const int* in_sizes, int n_in,
                              void* d_out, int out_size, void* d_ws, size_t ws_size,
                              hipStream_t stream)
{
    const int*   ids       = (const int*)d_in[0];
    const float* emb       = (const float*)d_in[1];
    const float* norm_w    = (const float*)d_in[2];
    const float* in_proj_w = (const float*)d_in[3];
    const float* conv_w    = (const float*)d_in[4];
    const float* conv_b    = (const float*)d_in[5];
    const float* x_proj_w  = (const float*)d_in[6];
    const float* dt_proj_w = (const float*)d_in[7];
    const float* dt_proj_b = (const float*)d_in[8];
    const float* A_log     = (const float*)d_in[9];
    const float* Dp        = (const float*)d_in[10];
    const float* out_proj_w= (const float*)d_in[11];

    float* x = (float*)d_out;                 // running residual (L x DM)

    // Workspace carve-up
    char* wsb = (char*)d_ws;
    auto alloc_f = [&](size_t n) { float* p = (float*)wsb; wsb += n * 4; return p; };
    auto alloc_s = [&](size_t n) { short* p = (short*)wsb; wsb += ((n * 2 + 15) & ~15ull); return p; };

    float* xz    = alloc_f((size_t)L_SEQ * 2 * DI);
    float* xr    = alloc_f((size_t)L_SEQ * DI);
    float* xdbl  = alloc_f((size_t)L_SEQ * XDW);
    float* delta = alloc_f((size_t)L_SEQ * DI);
    float* aprod = alloc_f((size_t)NCH * DI * DST);
    float* hfin  = alloc_f((size_t)NCH * DI * DST);
    float* hin   = alloc_f((size_t)NCH * DI * DST);
    short* xn_bf = alloc_s((size_t)L_SEQ * DM);
    short* y2_bf = alloc_s((size_t)L_SEQ * DI);
    short* ipw_t = alloc_s((size_t)2 * DI * DM);   // [3072][768]
    short* opw_t = alloc_s((size_t)DM * DI);       // [768][1536]

    // Embedding
    embed_kernel<<<(L_SEQ * (DM / 4) + 255) / 256, 256, 0, stream>>>(ids, emb, x);

    for (int layer = 0; layer < 2; layer++) {
        const float* nw  = norm_w     + (size_t)layer * DM;
        const float* ipw = in_proj_w  + (size_t)layer * DM * 2 * DI;
        const float* cw  = conv_w     + (size_t)layer * DI * 4;
        const float* cb  = conv_b     + (size_t)layer * DI;
        const float* xpw = x_proj_w   + (size_t)layer * DI * XDW;
        const float* dpw = dt_proj_w  + (size_t)layer * DTR * DI;
        const float* dpb = dt_proj_b  + (size_t)layer * DI;
        const float* al  = A_log      + (size_t)layer * DI * DST;
        const float* dpp = Dp         + (size_t)layer * DI;
        const float* opw = out_proj_w + (size_t)layer * DI * DM;

        // weight transpose+cast: ipw [768][3072] -> ipw_t [3072][768] bf16
        transpose_bf16_kernel<<<dim3(2 * DI / 32, DM / 32), 256, 0, stream>>>(
            ipw, ipw_t, DM, 2 * DI);
        // opw [1536][768] -> opw_t [768][1536] bf16
        transpose_bf16_kernel<<<dim3(DM / 32, DI / 32), 256, 0, stream>>>(
            opw, opw_t, DI, DM);

        // 1. RMSNorm -> bf16
        rmsnorm_kernel<<<L_SEQ, 256, 0, stream>>>(x, nw, xn_bf);

        // 2. xz = xn @ in_proj_w   (2048 x 3072, K=768) bf16 MFMA
        gemm_bf16_bt<0><<<dim3(2 * DI / 128, L_SEQ / 128), 256, 0, stream>>>(
            xn_bf, ipw_t, xz, L_SEQ, 2 * DI, DM);

        // 3. causal depthwise conv + silu -> xr
        conv_silu_kernel<<<(L_SEQ * DI) / 256, 256, 0, stream>>>(xz, cw, cb, xr);

        // 4. x_dbl = xr @ x_proj_w  (2048 x 80, K=1536) fp32
        gemm_f32<0><<<dim3((XDW + 63) / 64, L_SEQ / 64), 256, 0, stream>>>(
            xr, DI, xpw, XDW, xdbl, XDW, L_SEQ, XDW, DI, nullptr);

        // 5. delta = softplus(dt @ dt_proj_w + b)  (2048 x 1536, K=48) fp32
        gemm_f32<1><<<dim3(DI / 64, L_SEQ / 64), 256, 0, stream>>>(
            xdbl, XDW, dpw, DI, delta, DI, L_SEQ, DI, DTR, dpb);

        // 6. selective scan (3-pass chunked) fused with gating -> y2 bf16
        scan_passA<<<dim3(DI / 256, NCH), 256, 0, stream>>>(
            delta, xr, xdbl, al, aprod, hfin);
        scan_passB<<<(DI * DST) / 256, 256, 0, stream>>>(aprod, hfin, hin);
        scan_passC<<<dim3(DI / 256, NCH), 256, 0, stream>>>(
            delta, xr, xdbl, al, dpp, hin, xz, y2_bf);

        // 7. x += y2 @ out_proj_w  (2048 x 768, K=1536) bf16 MFMA
        gemm_bf16_bt<2><<<dim3(DM / 128, L_SEQ / 128), 256, 0, stream>>>(
            y2_bf, opw_t, x, L_SEQ, DM, DI);
    }
}

// Round 3
// 528.434 us; speedup vs baseline: 3.6882x; 1.9433x over previous
//
#include <hip/hip_runtime.h>
#include <math.h>

// Problem constants
#define L_SEQ 2048
#define DM    768
#define DI    1536          // d_inner
#define DTR   48            // dt_rank
#define DST   16            // d_state
#define XDW   80            // dt_rank + 2*d_state
#define NCH   64            // scan chunks
#define LC    32            // L_SEQ / NCH
#define XPS   8             // x_proj K-splits
#define XPK   (DI / XPS)    // 192

typedef short bf16x8 __attribute__((ext_vector_type(8)));
typedef float f32x4  __attribute__((ext_vector_type(4)));

__device__ __forceinline__ float silu_f(float x) {
    return x / (1.0f + __expf(-x));
}

// round-to-nearest-even float -> bf16 bits
__device__ __forceinline__ short f2bf(float x) {
    union { float f; unsigned u; } v; v.f = x;
    unsigned r = v.u + 0x7fff + ((v.u >> 16) & 1);
    return (short)(r >> 16);
}

// ---------------------------------------------------------------------------
// Embedding gather
// ---------------------------------------------------------------------------
__global__ __launch_bounds__(256) void embed_kernel(
    const int* __restrict__ ids, const float* __restrict__ emb,
    float* __restrict__ x)
{
    int idx = blockIdx.x * 256 + threadIdx.x;
    if (idx >= L_SEQ * (DM / 4)) return;
    int row = idx / (DM / 4);
    int col = idx % (DM / 4);
    ((float4*)x)[idx] = ((const float4*)emb)[(size_t)ids[row] * (DM / 4) + col];
}

// ---------------------------------------------------------------------------
// RMSNorm: one block per row; writes bf16 output (feeds bf16 MFMA GEMM)
// ---------------------------------------------------------------------------
__global__ __launch_bounds__(256) void rmsnorm_kernel(
    const float* __restrict__ x, const float* __restrict__ w,
    short* __restrict__ out)
{
    int row = blockIdx.x;
    const float* xr = x + (size_t)row * DM;
    float s = 0.f;
    for (int i = threadIdx.x; i < DM; i += 256) { float v = xr[i]; s += v * v; }
    #pragma unroll
    for (int off = 32; off > 0; off >>= 1) s += __shfl_down(s, off, 64);
    __shared__ float ws[4];
    int wave = threadIdx.x >> 6, lane = threadIdx.x & 63;
    if (lane == 0) ws[wave] = s;
    __syncthreads();
    float tot = ws[0] + ws[1] + ws[2] + ws[3];
    float rs = rsqrtf(tot / (float)DM + 1e-5f);
    for (int i = threadIdx.x; i < DM; i += 256)
        out[(size_t)row * DM + i] = f2bf(xr[i] * rs * w[i]);
}

// ---------------------------------------------------------------------------
// Transpose + fp32->bf16: W[K][N] -> Bt[N][K].  K,N multiples of 32.
// ---------------------------------------------------------------------------
__global__ __launch_bounds__(256) void transpose_bf16_kernel(
    const float* __restrict__ W, short* __restrict__ Bt, int K, int N)
{
    __shared__ float tile[32][33];
    int n0 = blockIdx.x * 32, k0 = blockIdx.y * 32;
    int tx = threadIdx.x & 31, ty = threadIdx.x >> 5;   // ty 0..7
    #pragma unroll
    for (int i = 0; i < 4; i++)
        tile[ty + i * 8][tx] = W[(size_t)(k0 + ty + i * 8) * N + n0 + tx];
    __syncthreads();
    #pragma unroll
    for (int i = 0; i < 4; i++)
        Bt[(size_t)(n0 + ty + i * 8) * K + k0 + tx] = f2bf(tile[tx][ty + i * 8]);
}

// ---------------------------------------------------------------------------
// x_proj weight transpose+cast: W[DI][XDW] -> Bt[XDW][DI] bf16
// ---------------------------------------------------------------------------
__global__ __launch_bounds__(256) void transpose_xpw_kernel(
    const float* __restrict__ W, short* __restrict__ Bt)
{
    int idx = blockIdx.x * 256 + threadIdx.x;   // over XDW*DI outputs
    if (idx >= XDW * DI) return;
    int j = idx / DI, k = idx % DI;
    Bt[idx] = f2bf(W[(size_t)k * XDW + j]);
}

// ---------------------------------------------------------------------------
// bf16 MFMA GEMM (m97 structure): C[M,N] = A[M,K] @ Bt[N,K]^T
// 128x128 tile, BK=32, 256 thr = 4 waves (2x2), 4x4 16x16x32 MFMA per wave.
//   MODE 0: C = acc      MODE 2: C += acc
// ---------------------------------------------------------------------------
template <int MODE>
__global__ __launch_bounds__(256) void gemm_bf16_bt(
    const short* __restrict__ A, const short* __restrict__ Bt,
    float* __restrict__ C, int M, int N, int K)
{
    __shared__ short As[128 * 32];
    __shared__ short Bs[128 * 32];
    int tid  = threadIdx.x;
    int lane = tid & 63;
    int w    = tid >> 6;
    int wr = w >> 1, wc = w & 1;
    int brow = blockIdx.y * 128, bcol = blockIdx.x * 128;

    f32x4 acc[4][4] = {};

    for (int k0 = 0; k0 < K; k0 += 32) {
        #pragma unroll
        for (int i = 0; i < 2; i++) {
            int c = tid + i * 256;        // 0..511 chunks of 16B
            int r = c >> 2, q = c & 3;
            const short* ga = A  + (size_t)(brow + r) * K + k0 + q * 8;
            const short* gb = Bt + (size_t)(bcol + r) * K + k0 + q * 8;
            __builtin_amdgcn_global_load_lds(
                (const __attribute__((address_space(1))) void*)ga,
                (__attribute__((address_space(3))) void*)&As[r * 32 + q * 8],
                16, 0, 0);
            __builtin_amdgcn_global_load_lds(
                (const __attribute__((address_space(1))) void*)gb,
                (__attribute__((address_space(3))) void*)&Bs[r * 32 + q * 8],
                16, 0, 0);
        }
        __syncthreads();

        bf16x8 af[4], bf[4];
        int kh = (lane >> 4) * 8;
        int ml = lane & 15;
        #pragma unroll
        for (int t = 0; t < 4; t++) {
            af[t] = *(const bf16x8*)&As[(wr * 64 + t * 16 + ml) * 32 + kh];
            bf[t] = *(const bf16x8*)&Bs[(wc * 64 + t * 16 + ml) * 32 + kh];
        }
        #pragma unroll
        for (int mt = 0; mt < 4; mt++)
            #pragma unroll
            for (int nt = 0; nt < 4; nt++)
                acc[mt][nt] = __builtin_amdgcn_mfma_f32_16x16x32_bf16(
                    af[mt], bf[nt], acc[mt][nt], 0, 0, 0);
        __syncthreads();
    }

    int r0 = (lane >> 4) * 4, c0 = lane & 15;
    #pragma unroll
    for (int mt = 0; mt < 4; mt++) {
        #pragma unroll
        for (int nt = 0; nt < 4; nt++) {
            #pragma unroll
            for (int reg = 0; reg < 4; reg++) {
                int row = brow + wr * 64 + mt * 16 + r0 + reg;
                int col = bcol + wc * 64 + nt * 16 + c0;
                float v = acc[mt][nt][reg];
                if (MODE == 0) C[(size_t)row * N + col] = v;
                else           C[(size_t)row * N + col] += v;
            }
        }
    }
}

// ---------------------------------------------------------------------------
// x_proj split-K MFMA: part[s][L][80] = xr_bf[:, ks] @ xpw_t[:, ks]^T
// Block: 4 waves; wave = 16 rows x 80 cols; grid (L/64, XPS)
// ---------------------------------------------------------------------------
__global__ __launch_bounds__(256) void xproj_splitk(
    const short* __restrict__ xr_bf,   // [L][DI]
    const short* __restrict__ xpw_t,   // [XDW][DI]
    float* __restrict__ part)          // [XPS][L][XDW]
{
    int w = threadIdx.x >> 6, lane = threadIdx.x & 63;
    int r0 = blockIdx.x * 64 + w * 16;
    int k0 = blockIdx.y * XPK;
    int ml = lane & 15, kh = (lane >> 4) * 8;

    f32x4 acc[5] = {};
    for (int ks = 0; ks < XPK; ks += 32) {
        bf16x8 a = *(const bf16x8*)&xr_bf[(size_t)(r0 + ml) * DI + k0 + ks + kh];
        #pragma unroll
        for (int t = 0; t < 5; t++) {
            bf16x8 b = *(const bf16x8*)&xpw_t[(size_t)(t * 16 + ml) * DI + k0 + ks + kh];
            acc[t] = __builtin_amdgcn_mfma_f32_16x16x32_bf16(a, b, acc[t], 0, 0, 0);
        }
    }
    float* po = part + (size_t)blockIdx.y * L_SEQ * XDW;
    int r_base = r0 + (lane >> 4) * 4;
    #pragma unroll
    for (int t = 0; t < 5; t++)
        #pragma unroll
        for (int reg = 0; reg < 4; reg++)
            po[(size_t)(r_base + reg) * XDW + t * 16 + ml] = acc[t][reg];
}

__global__ __launch_bounds__(256) void xproj_reduce(
    const float* __restrict__ part, float* __restrict__ xdbl)
{
    int idx = blockIdx.x * 256 + threadIdx.x;   // over L*XDW
    if (idx >= L_SEQ * XDW) return;
    float s = 0.f;
    #pragma unroll
    for (int p = 0; p < XPS; p++) s += part[(size_t)p * L_SEQ * XDW + idx];
    xdbl[idx] = s;
}

// ---------------------------------------------------------------------------
// Generic fp32 GEMM (dt_proj)
//   MODE 1: softplus(acc + bias[col])
// ---------------------------------------------------------------------------
template <int MODE>
__global__ __launch_bounds__(256) void gemm_f32(
    const float* __restrict__ A, int lda,
    const float* __restrict__ B, int ldb,
    float* __restrict__ C, int ldc,
    int M, int N, int K,
    const float* __restrict__ bias)
{
    const int BM = 64, BN = 64, BK = 16;
    __shared__ __align__(16) float As[BK][BM + 4];
    __shared__ __align__(16) float Bs[BK][BN + 4];
    int tid = threadIdx.x;
    int brow = blockIdx.y * BM;
    int bcol = blockIdx.x * BN;
    int ty = tid >> 4, tx = tid & 15;

    float acc[4][4] = {};

    for (int k0 = 0; k0 < K; k0 += BK) {
        #pragma unroll
        for (int i = 0; i < 4; i++) {
            int idx = tid + i * 256;
            int m = idx >> 4, k = idx & 15;
            int gm = brow + m, gk = k0 + k;
            As[k][m] = (gm < M && gk < K) ? A[(size_t)gm * lda + gk] : 0.f;
        }
        #pragma unroll
        for (int i = 0; i < 4; i++) {
            int idx = tid + i * 256;
            int k = idx >> 6, n = idx & 63;
            int gk = k0 + k, gn = bcol + n;
            Bs[k][n] = (gk < K && gn < N) ? B[(size_t)gk * ldb + gn] : 0.f;
        }
        __syncthreads();
        #pragma unroll
        for (int k = 0; k < BK; k++) {
            float4 av = *(const float4*)&As[k][ty * 4];
            float4 bv = *(const float4*)&Bs[k][tx * 4];
            float a[4] = {av.x, av.y, av.z, av.w};
            float b[4] = {bv.x, bv.y, bv.z, bv.w};
            #pragma unroll
            for (int i = 0; i < 4; i++)
                #pragma unroll
                for (int j = 0; j < 4; j++)
                    acc[i][j] += a[i] * b[j];
        }
        __syncthreads();
    }

    #pragma unroll
    for (int i = 0; i < 4; i++) {
        int row = brow + ty * 4 + i;
        if (row >= M) continue;
        #pragma unroll
        for (int j = 0; j < 4; j++) {
            int col = bcol + tx * 4 + j;
            if (col >= N) continue;
            float v = acc[i][j];
            if (MODE == 0) {
                C[(size_t)row * ldc + col] = v;
            } else {
                v += bias[col];
                C[(size_t)row * ldc + col] = (v > 20.f) ? v : log1pf(__expf(v));
            }
        }
    }
}

// ---------------------------------------------------------------------------
// Causal depthwise conv (width 4) + bias + SiLU; writes fp32 + bf16
// ---------------------------------------------------------------------------
__global__ __launch_bounds__(256) void conv_silu_kernel(
    const float* __restrict__ xz, const float* __restrict__ w,
    const float* __restrict__ b, float* __restrict__ xr,
    short* __restrict__ xr_bf)
{
    int idx = blockIdx.x * 256 + threadIdx.x;
    if (idx >= L_SEQ * DI) return;
    int l = idx / DI, c = idx % DI;
    float4 wc = ((const float4*)w)[c];
    const float* col = xz + c;
    float acc = b[c];
    if (l >= 3) {
        acc += wc.x * col[(size_t)(l - 3) * (2 * DI)]
             + wc.y * col[(size_t)(l - 2) * (2 * DI)]
             + wc.z * col[(size_t)(l - 1) * (2 * DI)]
             + wc.w * col[(size_t)l * (2 * DI)];
    } else {
        const float wv[4] = {wc.x, wc.y, wc.z, wc.w};
        for (int k = 0; k < 4; k++) {
            int ls = l - 3 + k;
            if (ls >= 0) acc += wv[k] * col[(size_t)ls * (2 * DI)];
        }
    }
    float v = silu_f(acc);
    xr[idx] = v;
    xr_bf[idx] = f2bf(v);
}

// ---------------------------------------------------------------------------
// Selective scan pass A
// ---------------------------------------------------------------------------
__global__ __launch_bounds__(256) void scan_passA(
    const float* __restrict__ delta, const float* __restrict__ xr,
    const float* __restrict__ xdbl, const float* __restrict__ A_log,
    float* __restrict__ aprod, float* __restrict__ hfin)
{
    int d = blockIdx.x * 256 + threadIdx.x;
    int c = blockIdx.y;
    if (d >= DI) return;

    float Alog[DST], Aloc[DST], h[DST], P[DST];
    *(float4*)&Alog[0]  = *(const float4*)&A_log[(size_t)d * DST + 0];
    *(float4*)&Alog[4]  = *(const float4*)&A_log[(size_t)d * DST + 4];
    *(float4*)&Alog[8]  = *(const float4*)&A_log[(size_t)d * DST + 8];
    *(float4*)&Alog[12] = *(const float4*)&A_log[(size_t)d * DST + 12];
    #pragma unroll
    for (int n = 0; n < DST; n++) { Aloc[n] = -__expf(Alog[n]); h[n] = 0.f; P[n] = 1.f; }

    int l0 = c * LC;
    for (int l = l0; l < l0 + LC; l++) {
        float dl = delta[(size_t)l * DI + d];
        float ul = xr[(size_t)l * DI + d];
        float du = dl * ul;
        float Bv[DST];
        const float4* B4 = (const float4*)(xdbl + (size_t)l * XDW + DTR);
        *(float4*)&Bv[0] = B4[0]; *(float4*)&Bv[4] = B4[1];
        *(float4*)&Bv[8] = B4[2]; *(float4*)&Bv[12] = B4[3];
        #pragma unroll
        for (int n = 0; n < DST; n++) {
            float da = __expf(dl * Aloc[n]);
            h[n] = h[n] * da + du * Bv[n];
            P[n] *= da;
        }
    }
    size_t base = ((size_t)c * DI + d) * DST;
    #pragma unroll
    for (int n = 0; n < DST; n += 4) {
        *(float4*)&aprod[base + n] = *(float4*)&P[n];
        *(float4*)&hfin[base + n]  = *(float4*)&h[n];
    }
}

// ---------------------------------------------------------------------------
// Pass B: sequential carry over chunks
// ---------------------------------------------------------------------------
__global__ __launch_bounds__(256) void scan_passB(
    const float* __restrict__ aprod, const float* __restrict__ hfin,
    float* __restrict__ hin)
{
    int idx = blockIdx.x * 256 + threadIdx.x;
    if (idx >= DI * DST) return;
    float cur = 0.f;
    for (int c = 0; c < NCH; c++) {
        size_t o = (size_t)c * DI * DST + idx;
        hin[o] = cur;
        cur = hfin[o] + aprod[o] * cur;
    }
}

// ---------------------------------------------------------------------------
// Pass C: replay chunk with carry; fuse y and gating; write bf16 y2
// ---------------------------------------------------------------------------
__global__ __launch_bounds__(256) void scan_passC(
    const float* __restrict__ delta, const float* __restrict__ xr,
    const float* __restrict__ xdbl, const float* __restrict__ A_log,
    const float* __restrict__ Dp, const float* __restrict__ hin,
    const float* __restrict__ xz, short* __restrict__ y2)
{
    int d = blockIdx.x * 256 + threadIdx.x;
    int c = blockIdx.y;
    if (d >= DI) return;

    float Alog[DST], Aloc[DST], h[DST];
    *(float4*)&Alog[0]  = *(const float4*)&A_log[(size_t)d * DST + 0];
    *(float4*)&Alog[4]  = *(const float4*)&A_log[(size_t)d * DST + 4];
    *(float4*)&Alog[8]  = *(const float4*)&A_log[(size_t)d * DST + 8];
    *(float4*)&Alog[12] = *(const float4*)&A_log[(size_t)d * DST + 12];
    size_t base = ((size_t)c * DI + d) * DST;
    #pragma unroll
    for (int n = 0; n < DST; n += 4) *(float4*)&h[n] = *(const float4*)&hin[base + n];
    #pragma unroll
    for (int n = 0; n < DST; n++) Aloc[n] = -__expf(Alog[n]);
    float Dd = Dp[d];

    int l0 = c * LC;
    for (int l = l0; l < l0 + LC; l++) {
        float dl = delta[(size_t)l * DI + d];
        float ul = xr[(size_t)l * DI + d];
        float du = dl * ul;
        float Bv[DST], Cv[DST];
        const float4* B4 = (const float4*)(xdbl + (size_t)l * XDW + DTR);
        const float4* C4 = (const float4*)(xdbl + (size_t)l * XDW + DTR + DST);
        *(float4*)&Bv[0] = B4[0]; *(float4*)&Bv[4] = B4[1];
        *(float4*)&Bv[8] = B4[2]; *(float4*)&Bv[12] = B4[3];
        *(float4*)&Cv[0] = C4[0]; *(float4*)&Cv[4] = C4[1];
        *(float4*)&Cv[8] = C4[2]; *(float4*)&Cv[12] = C4[3];
        float y = 0.f;
        #pragma unroll
        for (int n = 0; n < DST; n++) {
            float da = __expf(dl * Aloc[n]);
            h[n] = h[n] * da + du * Bv[n];
            y += h[n] * Cv[n];
        }
        y += ul * Dd;
        float r = xz[(size_t)l * (2 * DI) + DI + d];
        y2[(size_t)l * DI + d] = f2bf(y * silu_f(r));
    }
}

// ---------------------------------------------------------------------------
// Host launch
// ---------------------------------------------------------------------------
extern "C" void kernel_launch(void* const* d_in, const int* in_sizes, int n_in,
                              void* d_out, int out_size, void* d_ws, size_t ws_size,
                              hipStream_t stream)
{
    const int*   ids       = (const int*)d_in[0];
    const float* emb       = (const float*)d_in[1];
    const float* norm_w    = (const float*)d_in[2];
    const float* in_proj_w = (const float*)d_in[3];
    const float* conv_w    = (const float*)d_in[4];
    const float* conv_b    = (const float*)d_in[5];
    const float* x_proj_w  = (const float*)d_in[6];
    const float* dt_proj_w = (const float*)d_in[7];
    const float* dt_proj_b = (const float*)d_in[8];
    const float* A_log     = (const float*)d_in[9];
    const float* Dp        = (const float*)d_in[10];
    const float* out_proj_w= (const float*)d_in[11];

    float* x = (float*)d_out;                 // running residual (L x DM)

    // Workspace carve-up
    char* wsb = (char*)d_ws;
    auto alloc_f = [&](size_t n) { float* p = (float*)wsb; wsb += n * 4; return p; };
    auto alloc_s = [&](size_t n) { short* p = (short*)wsb; wsb += ((n * 2 + 15) & ~15ull); return p; };

    float* xz    = alloc_f((size_t)L_SEQ * 2 * DI);
    float* xr    = alloc_f((size_t)L_SEQ * DI);
    float* xdbl  = alloc_f((size_t)L_SEQ * XDW);
    float* delta = alloc_f((size_t)L_SEQ * DI);
    float* aprod = alloc_f((size_t)NCH * DI * DST);
    float* hfin  = alloc_f((size_t)NCH * DI * DST);
    float* hin   = alloc_f((size_t)NCH * DI * DST);
    float* xpart = alloc_f((size_t)XPS * L_SEQ * XDW);
    short* xn_bf = alloc_s((size_t)L_SEQ * DM);
    short* y2_bf = alloc_s((size_t)L_SEQ * DI);
    short* xr_bf = alloc_s((size_t)L_SEQ * DI);
    short* ipw_t = alloc_s((size_t)2 * DI * DM);   // [3072][768]
    short* opw_t = alloc_s((size_t)DM * DI);       // [768][1536]
    short* xpw_t = alloc_s((size_t)XDW * DI);      // [80][1536]

    // Embedding
    embed_kernel<<<(L_SEQ * (DM / 4) + 255) / 256, 256, 0, stream>>>(ids, emb, x);

    for (int layer = 0; layer < 2; layer++) {
        const float* nw  = norm_w     + (size_t)layer * DM;
        const float* ipw = in_proj_w  + (size_t)layer * DM * 2 * DI;
        const float* cw  = conv_w     + (size_t)layer * DI * 4;
        const float* cb  = conv_b     + (size_t)layer * DI;
        const float* xpw = x_proj_w   + (size_t)layer * DI * XDW;
        const float* dpw = dt_proj_w  + (size_t)layer * DTR * DI;
        const float* dpb = dt_proj_b  + (size_t)layer * DI;
        const float* al  = A_log      + (size_t)layer * DI * DST;
        const float* dpp = Dp         + (size_t)layer * DI;
        const float* opw = out_proj_w + (size_t)layer * DI * DM;

        // weight transposes / casts
        transpose_bf16_kernel<<<dim3(2 * DI / 32, DM / 32), 256, 0, stream>>>(
            ipw, ipw_t, DM, 2 * DI);
        transpose_bf16_kernel<<<dim3(DM / 32, DI / 32), 256, 0, stream>>>(
            opw, opw_t, DI, DM);
        transpose_xpw_kernel<<<(XDW * DI + 255) / 256, 256, 0, stream>>>(xpw, xpw_t);

        // 1. RMSNorm -> bf16
        rmsnorm_kernel<<<L_SEQ, 256, 0, stream>>>(x, nw, xn_bf);

        // 2. xz = xn @ in_proj_w   (2048 x 3072, K=768) bf16 MFMA
        gemm_bf16_bt<0><<<dim3(2 * DI / 128, L_SEQ / 128), 256, 0, stream>>>(
            xn_bf, ipw_t, xz, L_SEQ, 2 * DI, DM);

        // 3. causal depthwise conv + silu -> xr (fp32) + xr_bf (bf16)
        conv_silu_kernel<<<(L_SEQ * DI) / 256, 256, 0, stream>>>(xz, cw, cb, xr, xr_bf);

        // 4. x_dbl = xr @ x_proj_w  (2048 x 80, K=1536) split-K bf16 MFMA
        xproj_splitk<<<dim3(L_SEQ / 64, XPS), 256, 0, stream>>>(xr_bf, xpw_t, xpart);
        xproj_reduce<<<(L_SEQ * XDW + 255) / 256, 256, 0, stream>>>(xpart, xdbl);

        // 5. delta = softplus(dt @ dt_proj_w + b)  (2048 x 1536, K=48) fp32
        gemm_f32<1><<<dim3(DI / 64, L_SEQ / 64), 256, 0, stream>>>(
            xdbl, XDW, dpw, DI, delta, DI, L_SEQ, DI, DTR, dpb);

        // 6. selective scan (3-pass chunked) fused with gating -> y2 bf16
        scan_passA<<<dim3(DI / 256, NCH), 256, 0, stream>>>(
            delta, xr, xdbl, al, aprod, hfin);
        scan_passB<<<(DI * DST) / 256, 256, 0, stream>>>(aprod, hfin, hin);
        scan_passC<<<dim3(DI / 256, NCH), 256, 0, stream>>>(
            delta, xr, xdbl, al, dpp, hin, xz, y2_bf);

        // 7. x += y2 @ out_proj_w  (2048 x 768, K=1536) bf16 MFMA
        gemm_bf16_bt<2><<<dim3(DM / 128, L_SEQ / 128), 256, 0, stream>>>(
            y2_bf, opw_t, x, L_SEQ, DM, DI);
    }
}